// Round 2
// baseline (1635.176 us; speedup 1.0000x reference)
//
#include <hip/hip_runtime.h>

// Chamfer loss, B=8, N=M=8192, D=3, fp32 I/O — MFMA + pipelined staging (R4).
//
// R3 (44us pass1): MfmaUtil 31 / VALUBusy 45 / Occ 32 — nothing saturated.
// Gaps: (a) 2-barrier chunk structure leaves global-load latency unhidden,
// (b) every wave read every b-tile from LDS (4x redundant, ~10us/CU pipe),
// (c) fragment-format VALU redone by all 32 blocks sharing a b-half.
//
// R4: pass0 formats all points into the MFMA A-operand LDS image once
// (byte-identical math to R3 -> same numerics). Pass1: 8 chunks x 512 pts,
// double-buffered 2x16KB LDS, T14 split staging (loads issued before
// compute, ds_write after, ONE barrier per chunk). Waves partition b-tiles
// (4 each/chunk) and hold 8 a-frags = all 256 block a-points; cross-wave
// max via 4KB LDS epilogue. Floor: VALU fold 8 max3/MFMA ~= 6.8us/SIMD.
//
//   v_mfma_f32_32x32x16_f16, K-slots (13/16), coords pre-scaled x16:
//     b (A-op): k0-7 = bh_x bh_y bh_z bl_x bl_y bl_z bh_x bh_y
//               k8-15 = bh_z ch cl 1 1 0 0 0          (c = -0.5|b|^2 split)
//     a (B-op): k0-7 = ah_x ah_y ah_z ah_x ah_y ah_z al_x al_y
//               k8-15 = al_z 1 1 dh dl 0 0 0          (d = -0.5|a|^2 split)
//   => v = ab - |a|^2/2 - |b|^2/2 = -d2/2 (scaled 256); d2 = -max(v)/128.

#define BATCH   8
#define NPTS    8192
#define BLK     256
#define TOTAL_A (2 * BATCH * NPTS)            // 131072
#define NCH2    2                             // b-halves per (batch,dir)
#define BHALF   (NPTS / NCH2)                 // 4096
#define CHUNK   512                           // staged b-points per round
#define NCHUNK  (BHALF / CHUNK)               // 8
#define ABLKS   (NPTS / 256)                  // 32
#define P1_BLOCKS (2 * BATCH * ABLKS * NCH2)  // 1024
#define P2_BLOCKS (TOTAL_A / BLK)             // 512
#define SC      16.0f                         // exact pow2 coord scale

typedef _Float16 f16x8  __attribute__((ext_vector_type(8)));
typedef float    f32x16 __attribute__((ext_vector_type(16)));

static __device__ __forceinline__ unsigned int pk2(float a, float b) {
  unsigned short ua = __builtin_bit_cast(unsigned short, (_Float16)a);
  unsigned short ub = __builtin_bit_cast(unsigned short, (_Float16)b);
  return (unsigned int)ua | ((unsigned int)ub << 16);
}

// 16 accumulator values + running max -> 8 v_max3_f32
static __device__ __forceinline__ float fold16(float mq, f32x16 d) {
  float t0 = fmaxf(fmaxf(d[0],  d[1]),  d[2]);
  float t1 = fmaxf(fmaxf(d[3],  d[4]),  d[5]);
  float t2 = fmaxf(fmaxf(d[6],  d[7]),  d[8]);
  float t3 = fmaxf(fmaxf(d[9],  d[10]), d[11]);
  float t4 = fmaxf(fmaxf(d[12], d[13]), d[14]);
  float t5 = fmaxf(fmaxf(t0, t1), t2);
  float t6 = fmaxf(fmaxf(t3, t4), d[15]);
  return fmaxf(fmaxf(mq, t5), t6);
}

// b-point -> A-operand fragment pair (identical math to R3 stage_point)
static __device__ __forceinline__ void fmt_point(float X, float Y, float Z,
                                                 uint4* lo, uint4* hi) {
  float x = X * SC, y = Y * SC, z = Z * SC;
  float fx = (float)(_Float16)x, fy = (float)(_Float16)y, fz = (float)(_Float16)z;
  float lx = x - fx, ly = y - fy, lz = z - fz;
  float b2 = fmaf(x, x, fmaf(y, y, z * z));
  float c  = -0.5f * b2;
  float fc = (float)(_Float16)c;
  float lc = c - fc;
  *lo = make_uint4(pk2(x, y), pk2(z, lx), pk2(ly, lz), pk2(x, y));
  *hi = make_uint4(pk2(z, c), pk2(lc, 1.0f), 0x00003C00u, 0u);
}

// a-point -> B-operand fragment (col = lane&31, k-group = lane>>5)
static __device__ __forceinline__ f16x8 make_afrag(float X, float Y, float Z,
                                                   int hi) {
  float x = X * SC, y = Y * SC, z = Z * SC;
  float fx = (float)(_Float16)x, fy = (float)(_Float16)y, fz = (float)(_Float16)z;
  float lx = x - fx, ly = y - fy, lz = z - fz;
  float a2 = fmaf(x, x, fmaf(y, y, z * z));
  float dd = -0.5f * a2;
  float fd = (float)(_Float16)dd;
  float ld = dd - fd;
  uint4 u;
  if (!hi) {
    u = make_uint4(pk2(x, y), pk2(z, x), pk2(y, z), pk2(lx, ly));
  } else {
    u = make_uint4(pk2(lz, 1.0f), pk2(1.0f, dd), pk2(ld, 0.0f), 0u);
  }
  return __builtin_bit_cast(f16x8, u);
}

// pass0: format every point of both arrays into the fragment image.
// Layout (uint4 units): region = arr*8+batch (8192 pts, 16384 uint4):
//   pt p: lo at region*16384 + (p>>5)*64 + (p&31), hi at +32.
__global__ __launch_bounds__(BLK) void chamfer_fmt(
    const float* __restrict__ pred, const float* __restrict__ gt,
    uint4* __restrict__ fmt) {
  const int gid = blockIdx.x * BLK + threadIdx.x;   // [0, TOTAL_A)
  const int arr = gid >> 16;                        // 0=pred, 1=gt
  const int idx = gid & 65535;
  const float* src = arr ? gt : pred;
  float X = src[(size_t)idx * 3 + 0];
  float Y = src[(size_t)idx * 3 + 1];
  float Z = src[(size_t)idx * 3 + 2];
  uint4 lo, hi;
  fmt_point(X, Y, Z, &lo, &hi);
  const int region = gid >> 13;
  const int p      = gid & 8191;
  size_t base = (size_t)region * 16384 + (size_t)(p >> 5) * 64 + (p & 31);
  fmt[base]      = lo;
  fmt[base + 32] = hi;
}

__global__ __launch_bounds__(BLK, 4) void chamfer_mfma_pass1(
    const float* __restrict__ pred, const float* __restrict__ gt,
    const uint4* __restrict__ fmt, float* __restrict__ partial) {
  __shared__ uint4 lds4[CHUNK * 2 * 2];   // 2 buffers x 16KB
  uint4* bufA = lds4;
  uint4* bufB = lds4 + CHUNK * 2;

  const int bid   = blockIdx.x;
  const int bhalf = bid & 1;
  const int r     = bid >> 1;
  const int ablk  = r & (ABLKS - 1);
  const int bd    = r >> 5;           // 0..15 = side*8 + batch
  const int batch = bd & 7;
  const int side  = bd >> 3;

  const float* A = side ? gt : pred;
  // B-array for this side: side0 -> gt (arr1), side1 -> pred (arr0)
  const uint4* fmtB = fmt + (size_t)((1 - side) * 8 + batch) * 16384
                          + (size_t)bhalf * 8192;   // chunk c at + c*1024

  const int t    = threadIdx.x;
  const int lane = t & 63;
  const int wave = t >> 6;
  const int col  = lane & 31;
  const int hi   = lane >> 5;

  // 8 a-frags per wave = all 256 block a-points (a-pt = f*32 + col)
  const float* Ab = A + ((size_t)batch * NPTS + (size_t)ablk * 256) * 3;
  f16x8 af[8];
  float mq[8];
#pragma unroll
  for (int f = 0; f < 8; ++f) {
    int n = f * 32 + col;
    af[f] = make_afrag(Ab[n * 3 + 0], Ab[n * 3 + 1], Ab[n * 3 + 2], hi);
    mq[f] = -3.0e38f;
  }

  const f32x16 zero = {};

  // prologue: stage chunk 0 into bufA
  {
    const uint4* src = fmtB;
#pragma unroll
    for (int k = 0; k < 4; ++k) bufA[t + k * 256] = src[t + k * 256];
  }
  __syncthreads();

  uint4 st[4];
  for (int c = 0; c < NCHUNK; ++c) {
    uint4* rbuf = (c & 1) ? bufB : bufA;
    uint4* wbuf = (c & 1) ? bufA : bufB;

    // T14: issue next chunk's global loads BEFORE compute
    if (c + 1 < NCHUNK) {
      const uint4* src = fmtB + (size_t)(c + 1) * 1024;
#pragma unroll
      for (int k = 0; k < 4; ++k) st[k] = src[t + k * 256];
    }

    // compute: this wave owns 4 of the chunk's 16 tiles
    const uint4* tbase = rbuf + wave * 4 * 64 + lane;
#pragma unroll
    for (int tt = 0; tt < 4; ++tt) {
      f16x8 bf = *(const f16x8*)(tbase + tt * 64);
#pragma unroll
      for (int f = 0; f < 8; ++f) {
        f32x16 d = __builtin_amdgcn_mfma_f32_32x32x16_f16(bf, af[f], zero, 0, 0, 0);
        mq[f] = fold16(mq[f], d);
      }
    }

    // write-late into the other buffer, single barrier per chunk
    if (c + 1 < NCHUNK) {
#pragma unroll
      for (int k = 0; k < 4; ++k) wbuf[t + k * 256] = st[k];
    }
    __syncthreads();
  }

  // lanes l and l+32 hold the same a-col over disjoint b-rows
#pragma unroll
  for (int f = 0; f < 8; ++f) mq[f] = fmaxf(mq[f], __shfl_xor(mq[f], 32));

  // cross-wave max: [wave][a-pt] in LDS (reuse buffer)
  float* red = (float*)lds4;
  if (lane < 32) {
#pragma unroll
    for (int f = 0; f < 8; ++f) red[wave * 256 + f * 32 + col] = mq[f];
  }
  __syncthreads();

  float m = fmaxf(fmaxf(red[t], red[256 + t]), fmaxf(red[512 + t], red[768 + t]));
  partial[((size_t)bd * NPTS + (size_t)ablk * 256 + t) * NCH2 + bhalf] = m;
}

__global__ __launch_bounds__(BLK) void chamfer_mfma_pass2(
    const float2* __restrict__ partial, float* __restrict__ blockSums) {
  const int gid = blockIdx.x * BLK + threadIdx.x;   // [0, TOTAL_A)
  float2 p = partial[gid];
  // v = -d2_scaled/2, scale = 256  =>  d2 = max(v0,v1) * (-1/128), clamp 0
  float d2 = fmaxf(fmaxf(p.x, p.y) * (-1.0f / 128.0f), 0.0f);

  float v = d2;
  for (int off = 32; off > 0; off >>= 1) v += __shfl_down(v, off);
  __shared__ float wsum[BLK / 64];
  int lane = threadIdx.x & 63, wv = threadIdx.x >> 6;
  if (lane == 0) wsum[wv] = v;
  __syncthreads();
  if (wv == 0) {
    float s = (lane < (BLK / 64)) ? wsum[lane] : 0.0f;
    for (int off = 2; off > 0; off >>= 1) s += __shfl_down(s, off);
    if (lane == 0) blockSums[blockIdx.x] = s;
  }
}

__global__ __launch_bounds__(BLK) void chamfer_pass3(
    const float* __restrict__ blockSums, float* __restrict__ out) {
  const int t = threadIdx.x;
  float v = blockSums[t] + blockSums[t + BLK];   // 512 sums
  for (int off = 32; off > 0; off >>= 1) v += __shfl_down(v, off);
  __shared__ float wsum[BLK / 64];
  int lane = t & 63, wv = t >> 6;
  if (lane == 0) wsum[wv] = v;
  __syncthreads();
  if (t == 0) {
    float s = wsum[0] + wsum[1] + wsum[2] + wsum[3];
    out[0] = s * (1.0f / (float)TOTAL_A);   // (sum1+sum2)/(2*65536)
  }
}

extern "C" void kernel_launch(void* const* d_in, const int* in_sizes, int n_in,
                              void* d_out, int out_size, void* d_ws, size_t ws_size,
                              hipStream_t stream) {
  const float* pred = (const float*)d_in[0];
  const float* gt   = (const float*)d_in[1];
  float* out = (float*)d_out;

  uint4* fmt       = (uint4*)d_ws;                        // 131072*32B = 4MB
  float* partial   = (float*)d_ws + TOTAL_A * 8;          // +1MB
  float* blockSums = partial + (size_t)TOTAL_A * NCH2;    // +2KB

  chamfer_fmt<<<TOTAL_A / BLK, BLK, 0, stream>>>(pred, gt, fmt);
  chamfer_mfma_pass1<<<P1_BLOCKS, BLK, 0, stream>>>(pred, gt, fmt, partial);
  chamfer_mfma_pass2<<<P2_BLOCKS, BLK, 0, stream>>>((const float2*)partial, blockSums);
  chamfer_pass3<<<1, BLK, 0, stream>>>(blockSums, out);
}

// Round 3
// 1121.906 us; speedup vs baseline: 1.4575x; 1.4575x over previous
//
#include <hip/hip_runtime.h>

// Chamfer loss, B=8, N=M=8192, D=3, fp32 I/O — MFMA, spill-safe (R5).
//
// R4 post-mortem: WRITE_SIZE 3.9GB from a kernel writing 0.5MB = scratch
// spills (af[8]+st[4]+acc vs __launch_bounds__(256,4)'s 128-reg cap,
// VGPR_Count=64 after VGPR/AGPR split). R5 keeps R4's structure but fits
// the budget: af[4]/mq[4]/st[4] (~85 regs), launch_bounds(256,2).
//
// Layout: pass0 formats all points into the MFMA A-operand image once.
// Pass1: one block per 256 a-pts, FULL 8192-pt b-range (NCH2=1) streamed
// through 2x16KB double-buffered LDS, 1 barrier/chunk, T14 load-early/
// write-late. Waves: (g,q) = (a-half, tile-parity): each wave holds 4
// a-frags (128 a-pts) and reads only every other tile -> 2x fewer LDS
// reads than R3. Epilogue: xor32 + cross-wave LDS max -> d2 -> block sum
// -> last-block (threadfence+atomic) does the final 512-sum reduce with
// the SAME tree order as R3's pass2/pass3 (bitwise-identical result).
// Dispatches: 2 (was 4).
//
//   v_mfma_f32_32x32x16_f16, K-slots (13/16), coords pre-scaled x16:
//     b (A-op): k0-7 = bh_x bh_y bh_z bl_x bl_y bl_z bh_x bh_y
//               k8-15 = bh_z ch cl 1 1 0 0 0          (c = -0.5|b|^2 split)
//     a (B-op): k0-7 = ah_x ah_y ah_z ah_x ah_y ah_z al_x al_y
//               k8-15 = al_z 1 1 dh dl 0 0 0          (d = -0.5|a|^2 split)
//   => v = -d2/2 (scaled 256); d2 = max(v)* (-1/128), clamp 0.

#define BATCH   8
#define NPTS    8192
#define BLK     256
#define TOTAL_A (2 * BATCH * NPTS)            // 131072
#define CHUNK   512                           // staged b-points per round
#define NCHUNK  (NPTS / CHUNK)                // 16
#define ABLKS   (NPTS / 256)                  // 32
#define P1_BLOCKS (2 * BATCH * ABLKS)         // 512
#define SC      16.0f                         // exact pow2 coord scale

typedef _Float16 f16x8  __attribute__((ext_vector_type(8)));
typedef float    f32x16 __attribute__((ext_vector_type(16)));

static __device__ __forceinline__ unsigned int pk2(float a, float b) {
  unsigned short ua = __builtin_bit_cast(unsigned short, (_Float16)a);
  unsigned short ub = __builtin_bit_cast(unsigned short, (_Float16)b);
  return (unsigned int)ua | ((unsigned int)ub << 16);
}

// 16 accumulator values + running max -> 8 v_max3_f32
static __device__ __forceinline__ float fold16(float mq, f32x16 d) {
  float t0 = fmaxf(fmaxf(d[0],  d[1]),  d[2]);
  float t1 = fmaxf(fmaxf(d[3],  d[4]),  d[5]);
  float t2 = fmaxf(fmaxf(d[6],  d[7]),  d[8]);
  float t3 = fmaxf(fmaxf(d[9],  d[10]), d[11]);
  float t4 = fmaxf(fmaxf(d[12], d[13]), d[14]);
  float t5 = fmaxf(fmaxf(t0, t1), t2);
  float t6 = fmaxf(fmaxf(t3, t4), d[15]);
  return fmaxf(fmaxf(mq, t5), t6);
}

// b-point -> A-operand fragment pair (byte-identical to R3/R4 -> absmax 0)
static __device__ __forceinline__ void fmt_point(float X, float Y, float Z,
                                                 uint4* lo, uint4* hi) {
  float x = X * SC, y = Y * SC, z = Z * SC;
  float fx = (float)(_Float16)x, fy = (float)(_Float16)y, fz = (float)(_Float16)z;
  float lx = x - fx, ly = y - fy, lz = z - fz;
  float b2 = fmaf(x, x, fmaf(y, y, z * z));
  float c  = -0.5f * b2;
  float fc = (float)(_Float16)c;
  float lc = c - fc;
  *lo = make_uint4(pk2(x, y), pk2(z, lx), pk2(ly, lz), pk2(x, y));
  *hi = make_uint4(pk2(z, c), pk2(lc, 1.0f), 0x00003C00u, 0u);
}

// a-point -> B-operand fragment (col = lane&31, k-group = lane>>5)
static __device__ __forceinline__ f16x8 make_afrag(float X, float Y, float Z,
                                                   int hi) {
  float x = X * SC, y = Y * SC, z = Z * SC;
  float fx = (float)(_Float16)x, fy = (float)(_Float16)y, fz = (float)(_Float16)z;
  float lx = x - fx, ly = y - fy, lz = z - fz;
  float a2 = fmaf(x, x, fmaf(y, y, z * z));
  float dd = -0.5f * a2;
  float fd = (float)(_Float16)dd;
  float ld = dd - fd;
  uint4 u;
  if (!hi) {
    u = make_uint4(pk2(x, y), pk2(z, x), pk2(y, z), pk2(lx, ly));
  } else {
    u = make_uint4(pk2(lz, 1.0f), pk2(1.0f, dd), pk2(ld, 0.0f), 0u);
  }
  return __builtin_bit_cast(f16x8, u);
}

// pass0: format every point. Region = arr*8+batch (16384 uint4):
//   pt p: lo at region*16384 + (p>>5)*64 + (p&31), hi at +32.
__global__ __launch_bounds__(BLK) void chamfer_fmt(
    const float* __restrict__ pred, const float* __restrict__ gt,
    uint4* __restrict__ fmt, unsigned int* __restrict__ counter) {
  const int gid = blockIdx.x * BLK + threadIdx.x;   // [0, TOTAL_A)
  if (gid == 0) *counter = 0u;                      // reset for pass1
  const int arr = gid >> 16;                        // 0=pred, 1=gt
  const int idx = gid & 65535;
  const float* src = arr ? gt : pred;
  float X = src[(size_t)idx * 3 + 0];
  float Y = src[(size_t)idx * 3 + 1];
  float Z = src[(size_t)idx * 3 + 2];
  uint4 lo, hi;
  fmt_point(X, Y, Z, &lo, &hi);
  const int region = gid >> 13;
  const int p      = gid & 8191;
  size_t base = (size_t)region * 16384 + (size_t)(p >> 5) * 64 + (p & 31);
  fmt[base]      = lo;
  fmt[base + 32] = hi;
}

__global__ __launch_bounds__(BLK, 2) void chamfer_mfma_pass1(
    const float* __restrict__ pred, const float* __restrict__ gt,
    const uint4* __restrict__ fmt, float* __restrict__ blockSums,
    unsigned int* __restrict__ counter, float* __restrict__ out) {
  __shared__ uint4 lds4[2 * 1024];     // 2 x 16KB double buffer
  __shared__ float red[4 * 128];
  __shared__ float wsum[4];
  __shared__ int amLast;

  const int bid   = blockIdx.x;        // 512 = 2*8*32
  const int ablk  = bid & (ABLKS - 1);
  const int bd    = bid >> 5;          // side*8 + batch
  const int batch = bd & 7;
  const int side  = bd >> 3;

  const float* A    = side ? gt : pred;
  const uint4* fmtB = fmt + (size_t)((1 - side) * 8 + batch) * 16384;

  const int t    = threadIdx.x;
  const int lane = t & 63;
  const int wave = t >> 6;
  const int col  = lane & 31;
  const int hi   = lane >> 5;
  const int q    = wave & 1;           // tile parity
  const int g    = wave >> 1;          // a-half (128 pts)

  // 4 a-frags: a-pts g*128 + f*32 + col
  const float* Ab = A + ((size_t)batch * NPTS + (size_t)ablk * 256 + (size_t)g * 128) * 3;
  f16x8 af[4];
  float mq[4];
#pragma unroll
  for (int f = 0; f < 4; ++f) {
    int n = f * 32 + col;
    af[f] = make_afrag(Ab[n * 3 + 0], Ab[n * 3 + 1], Ab[n * 3 + 2], hi);
    mq[f] = -3.0e38f;
  }

  const f32x16 zero = {};
  uint4* bufA = lds4;
  uint4* bufB = lds4 + 1024;

  // prologue: stage chunk 0
#pragma unroll
  for (int k = 0; k < 4; ++k) bufA[t + k * 256] = fmtB[t + k * 256];
  __syncthreads();

  uint4 st[4];
  for (int c = 0; c < NCHUNK; ++c) {
    uint4* rbuf = (c & 1) ? bufB : bufA;
    uint4* wbuf = (c & 1) ? bufA : bufB;

    // T14: issue next chunk's loads before compute
    if (c + 1 < NCHUNK) {
      const uint4* src = fmtB + (size_t)(c + 1) * 1024;
#pragma unroll
      for (int k = 0; k < 4; ++k) st[k] = src[t + k * 256];
    }

    // wave computes tiles {q, q+2, ..., q+14}: 8 reads, 32 MFMA
    const uint4* tb = rbuf + q * 64 + lane;
#pragma unroll
    for (int tt = 0; tt < 8; ++tt) {
      f16x8 bf = *(const f16x8*)(tb + tt * 128);
#pragma unroll
      for (int f = 0; f < 4; ++f) {
        f32x16 d = __builtin_amdgcn_mfma_f32_32x32x16_f16(bf, af[f], zero, 0, 0, 0);
        mq[f] = fold16(mq[f], d);
      }
    }

    // write-late, single barrier per chunk
    if (c + 1 < NCHUNK) {
#pragma unroll
      for (int k = 0; k < 4; ++k) wbuf[t + k * 256] = st[k];
    }
    __syncthreads();
  }

  // lanes l, l+32: disjoint b-rows of the same a-col
#pragma unroll
  for (int f = 0; f < 4; ++f) mq[f] = fmaxf(mq[f], __shfl_xor(mq[f], 32));

  // cross-wave (tile-parity) max via LDS
  if (lane < 32) {
#pragma unroll
    for (int f = 0; f < 4; ++f) red[wave * 128 + f * 32 + col] = mq[f];
  }
  __syncthreads();

  const int g2 = t >> 7, loc = t & 127;
  float m  = fmaxf(red[(2 * g2) * 128 + loc], red[(2 * g2 + 1) * 128 + loc]);
  float d2 = fmaxf(m * (-1.0f / 128.0f), 0.0f);

  // block sum (same tree order as R3 pass2)
  float v = d2;
  for (int off = 32; off > 0; off >>= 1) v += __shfl_down(v, off);
  if (lane == 0) wsum[wave] = v;
  __syncthreads();
  if (t == 0) {
    float s = (wsum[0] + wsum[2]) + (wsum[1] + wsum[3]);
    blockSums[bid] = s;
    __threadfence();
    unsigned int prev = atomicAdd(counter, 1u);
    amLast = (prev == P1_BLOCKS - 1);
  }
  __syncthreads();

  // deterministic final reduce by the last block (same order as R3 pass3)
  if (amLast) {
    __threadfence();
    const volatile float* vbs = blockSums;
    float v2 = vbs[t] + vbs[t + 256];
    for (int off = 32; off > 0; off >>= 1) v2 += __shfl_down(v2, off);
    if (lane == 0) wsum[wave] = v2;
    __syncthreads();
    if (t == 0) {
      float s = ((wsum[0] + wsum[1]) + wsum[2]) + wsum[3];
      out[0] = s * (1.0f / (float)TOTAL_A);   // (sum1+sum2)/(2*65536)
    }
  }
}

extern "C" void kernel_launch(void* const* d_in, const int* in_sizes, int n_in,
                              void* d_out, int out_size, void* d_ws, size_t ws_size,
                              hipStream_t stream) {
  const float* pred = (const float*)d_in[0];
  const float* gt   = (const float*)d_in[1];
  float* out = (float*)d_out;

  uint4*        fmtb      = (uint4*)d_ws;                                  // 4 MB
  float*        blockSums = (float*)((char*)d_ws + (size_t)TOTAL_A * 32);  // +2 KB
  unsigned int* counter   = (unsigned int*)(blockSums + P1_BLOCKS);

  chamfer_fmt<<<TOTAL_A / BLK, BLK, 0, stream>>>(pred, gt, fmtb, counter);
  chamfer_mfma_pass1<<<P1_BLOCKS, BLK, 0, stream>>>(pred, gt, fmtb, blockSums,
                                                    counter, out);
}

// Round 4
// 104.095 us; speedup vs baseline: 15.7085x; 10.7777x over previous
//
#include <hip/hip_runtime.h>

// Chamfer loss, B=8, N=M=8192, D=3, fp32 I/O — MFMA R6.
//
// R4/R5 post-mortem: 4- and 8-accumulator-chain inner loops spill the
// in-flight f32x16 MFMA results to scratch (WRITE_SIZE 2.6-3.9GB vs 2KB
// legit). R3's 2-chain shape (af0/af1, mq0/mq1, 2 MFMA + 2 folds per
// tile) compiled to 44 VGPR, zero scratch. R6 keeps that inner loop
// EXACTLY and changes only zero-register-cost structure:
//   - pass0 pre-formats all points into the MFMA A-operand image (once,
//     byte-identical math -> same numerics as R3/R5, absmax was 0).
//   - staging via __builtin_amdgcn_global_load_lds width=16 (no VGPR
//     round-trip); fmt image is already in linear fragment order, which
//     is exactly the wave-uniform-base + lane*16 order the DMA writes.
//   - full 8192-pt b-range per block (NCH2=1): 512 blocks x 256 a-pts,
//     2x b-reuse (fetch 134MB), single-kernel finish via atomic
//     last-block reduce (R5-proven), 2 dispatches total.
//   - bijective XCD swizzle: each XCD's 64 blocks touch 2 fmt regions
//     (512KB) -> L2-resident.
//   - double-buffered 2x16KB LDS, stage(c+1) issued before compute(c),
//     ONE __syncthreads per chunk (compiler drains vmcnt at barrier).
//
//   v_mfma_f32_32x32x16_f16, K-slots (13/16), coords pre-scaled x16:
//     b (A-op): k0-7 = bh_x bh_y bh_z bl_x bl_y bl_z bh_x bh_y
//               k8-15 = bh_z ch cl 1 1 0 0 0          (c = -0.5|b|^2 split)
//     a (B-op): k0-7 = ah_x ah_y ah_z ah_x ah_y ah_z al_x al_y
//               k8-15 = al_z 1 1 dh dl 0 0 0          (d = -0.5|a|^2 split)
//   => v = -d2/2 (scaled 256); d2 = max_b(v) * (-1/128), clamp 0.

#define BATCH   8
#define NPTS    8192
#define BLK     256
#define TOTAL_A (2 * BATCH * NPTS)            // 131072
#define CHUNK   512                           // staged b-points per round
#define NCHUNK  (NPTS / CHUNK)                // 16
#define TPC     (CHUNK / 32)                  // 16 tiles per chunk
#define ABLKS   (NPTS / 256)                  // 32
#define P1_BLOCKS (2 * BATCH * ABLKS)         // 512
#define SC      16.0f                         // exact pow2 coord scale

typedef _Float16 f16x8  __attribute__((ext_vector_type(8)));
typedef float    f32x16 __attribute__((ext_vector_type(16)));
typedef __attribute__((address_space(1))) const void gptr_t;
typedef __attribute__((address_space(3))) void lptr_t;

static __device__ __forceinline__ unsigned int pk2(float a, float b) {
  unsigned short ua = __builtin_bit_cast(unsigned short, (_Float16)a);
  unsigned short ub = __builtin_bit_cast(unsigned short, (_Float16)b);
  return (unsigned int)ua | ((unsigned int)ub << 16);
}

// 16 accumulator values + running max -> 8 v_max3_f32
static __device__ __forceinline__ float fold16(float mq, f32x16 d) {
  float t0 = fmaxf(fmaxf(d[0],  d[1]),  d[2]);
  float t1 = fmaxf(fmaxf(d[3],  d[4]),  d[5]);
  float t2 = fmaxf(fmaxf(d[6],  d[7]),  d[8]);
  float t3 = fmaxf(fmaxf(d[9],  d[10]), d[11]);
  float t4 = fmaxf(fmaxf(d[12], d[13]), d[14]);
  float t5 = fmaxf(fmaxf(t0, t1), t2);
  float t6 = fmaxf(fmaxf(t3, t4), d[15]);
  return fmaxf(fmaxf(mq, t5), t6);
}

// b-point -> A-operand fragment pair (byte-identical to R3/R5)
static __device__ __forceinline__ void fmt_point(float X, float Y, float Z,
                                                 uint4* lo, uint4* hi) {
  float x = X * SC, y = Y * SC, z = Z * SC;
  float fx = (float)(_Float16)x, fy = (float)(_Float16)y, fz = (float)(_Float16)z;
  float lx = x - fx, ly = y - fy, lz = z - fz;
  float b2 = fmaf(x, x, fmaf(y, y, z * z));
  float c  = -0.5f * b2;
  float fc = (float)(_Float16)c;
  float lc = c - fc;
  *lo = make_uint4(pk2(x, y), pk2(z, lx), pk2(ly, lz), pk2(x, y));
  *hi = make_uint4(pk2(z, c), pk2(lc, 1.0f), 0x00003C00u, 0u);
}

// a-point -> B-operand fragment (col = lane&31, k-group = lane>>5)
static __device__ __forceinline__ f16x8 make_afrag(float X, float Y, float Z,
                                                   int hi) {
  float x = X * SC, y = Y * SC, z = Z * SC;
  float fx = (float)(_Float16)x, fy = (float)(_Float16)y, fz = (float)(_Float16)z;
  float lx = x - fx, ly = y - fy, lz = z - fz;
  float a2 = fmaf(x, x, fmaf(y, y, z * z));
  float dd = -0.5f * a2;
  float fd = (float)(_Float16)dd;
  float ld = dd - fd;
  uint4 u;
  if (!hi) {
    u = make_uint4(pk2(x, y), pk2(z, x), pk2(y, z), pk2(lx, ly));
  } else {
    u = make_uint4(pk2(lz, 1.0f), pk2(1.0f, dd), pk2(ld, 0.0f), 0u);
  }
  return __builtin_bit_cast(f16x8, u);
}

// pass0: format every point. Region = arr*8+batch (16384 uint4):
//   pt p: lo at region*16384 + (p>>5)*64 + (p&31), hi at +32.
__global__ __launch_bounds__(BLK) void chamfer_fmt(
    const float* __restrict__ pred, const float* __restrict__ gt,
    uint4* __restrict__ fmt, unsigned int* __restrict__ counter) {
  const int gid = blockIdx.x * BLK + threadIdx.x;   // [0, TOTAL_A)
  if (gid == 0) *counter = 0u;                      // reset for pass1
  const int arr = gid >> 16;                        // 0=pred, 1=gt
  const int idx = gid & 65535;
  const float* src = arr ? gt : pred;
  float X = src[(size_t)idx * 3 + 0];
  float Y = src[(size_t)idx * 3 + 1];
  float Z = src[(size_t)idx * 3 + 2];
  uint4 lo, hi;
  fmt_point(X, Y, Z, &lo, &hi);
  const int region = gid >> 13;
  const int p      = gid & 8191;
  size_t base = (size_t)region * 16384 + (size_t)(p >> 5) * 64 + (p & 31);
  fmt[base]      = lo;
  fmt[base + 32] = hi;
}

// stage one 16KB chunk (1024 uint4) via global_load_lds; wave w owns
// uint4 [w*256, w*256+256): 4 calls x 64 lanes x 16B, linear order.
static __device__ __forceinline__ void stage_chunk(const uint4* src,
                                                   uint4* dst,
                                                   int wave, int lane) {
#pragma unroll
  for (int k = 0; k < 4; ++k) {
    const uint4* g = src + wave * 256 + k * 64 + lane;
    uint4*       l = dst + wave * 256 + k * 64;
    __builtin_amdgcn_global_load_lds((gptr_t*)g, (lptr_t*)l, 16, 0, 0);
  }
}

__global__ __launch_bounds__(BLK, 4) void chamfer_mfma_pass1(
    const float* __restrict__ pred, const float* __restrict__ gt,
    const uint4* __restrict__ fmt, float* __restrict__ blockSums,
    unsigned int* __restrict__ counter, float* __restrict__ out) {
  __shared__ uint4 lds4[2 * 1024];     // 2 x 16KB double buffer
  __shared__ float wsum[4];
  __shared__ int amLast;

  // bijective XCD swizzle (512 % 8 == 0): XCD x gets 64 consecutive wgids
  const int swz   = ((blockIdx.x & 7) << 6) | (blockIdx.x >> 3);
  const int ablk  = swz & (ABLKS - 1);
  const int bd    = swz >> 5;          // side*8 + batch
  const int batch = bd & 7;
  const int side  = bd >> 3;

  const float* A    = side ? gt : pred;
  const uint4* fmtB = fmt + (size_t)((1 - side) * 8 + batch) * 16384;

  const int t    = threadIdx.x;
  const int lane = t & 63;
  const int wave = t >> 6;
  const int col  = lane & 31;
  const int hi   = lane >> 5;

  // R3-proven shape: 2 named a-frags / 2 named accumulator chains
  const float* Ab = A + ((size_t)batch * NPTS + (size_t)ablk * 256 + (size_t)wave * 64) * 3;
  f16x8 af0 = make_afrag(Ab[col * 3 + 0], Ab[col * 3 + 1], Ab[col * 3 + 2], hi);
  f16x8 af1 = make_afrag(Ab[(32 + col) * 3 + 0], Ab[(32 + col) * 3 + 1],
                         Ab[(32 + col) * 3 + 2], hi);
  float mq0 = -3.0e38f, mq1 = -3.0e38f;
  const f32x16 zero = {};

  // prologue: stage chunk 0 into buffer 0
  stage_chunk(fmtB, lds4, wave, lane);
  __syncthreads();

  for (int c = 0; c < NCHUNK; ++c) {
    const uint4* rbuf = lds4 + (c & 1) * 1024;
    // issue next chunk's DMA into the other buffer (safe: prior barrier
    // guarantees everyone finished reading it)
    if (c + 1 < NCHUNK)
      stage_chunk(fmtB + (size_t)(c + 1) * 1024, lds4 + ((c + 1) & 1) * 1024,
                  wave, lane);

#pragma unroll
    for (int tt = 0; tt < TPC; ++tt) {
      f16x8 bf = *(const f16x8*)(rbuf + tt * 64 + lane);
      f32x16 d0 = __builtin_amdgcn_mfma_f32_32x32x16_f16(bf, af0, zero, 0, 0, 0);
      f32x16 d1 = __builtin_amdgcn_mfma_f32_32x32x16_f16(bf, af1, zero, 0, 0, 0);
      mq0 = fold16(mq0, d0);
      mq1 = fold16(mq1, d1);
    }
    __syncthreads();   // drains vmcnt -> next buffer ready for all waves
  }

  // lanes l, l+32: disjoint b-rows of the same a-col
  mq0 = fmaxf(mq0, __shfl_xor(mq0, 32));
  mq1 = fmaxf(mq1, __shfl_xor(mq1, 32));

  // each wave owns its 64 a-pts -> d2 and block sum directly
  float v = 0.0f;
  if (lane < 32) {
    float d20 = fmaxf(mq0 * (-1.0f / 128.0f), 0.0f);
    float d21 = fmaxf(mq1 * (-1.0f / 128.0f), 0.0f);
    v = d20 + d21;
  }
  for (int off = 32; off > 0; off >>= 1) v += __shfl_down(v, off);
  if (lane == 0) wsum[wave] = v;
  __syncthreads();
  if (t == 0) {
    float s = (wsum[0] + wsum[1]) + (wsum[2] + wsum[3]);
    blockSums[swz] = s;
    __threadfence();
    unsigned int prev = atomicAdd(counter, 1u);
    amLast = (prev == P1_BLOCKS - 1);
  }
  __syncthreads();

  // deterministic final reduce by the last block
  if (amLast) {
    __threadfence();
    const volatile float* vbs = blockSums;
    float v2 = vbs[t] + vbs[t + 256];
    for (int off = 32; off > 0; off >>= 1) v2 += __shfl_down(v2, off);
    if (lane == 0) wsum[wave] = v2;
    __syncthreads();
    if (t == 0) {
      float s = ((wsum[0] + wsum[1]) + wsum[2]) + wsum[3];
      out[0] = s * (1.0f / (float)TOTAL_A);   // (sum1+sum2)/(2*65536)
    }
  }
}

extern "C" void kernel_launch(void* const* d_in, const int* in_sizes, int n_in,
                              void* d_out, int out_size, void* d_ws, size_t ws_size,
                              hipStream_t stream) {
  const float* pred = (const float*)d_in[0];
  const float* gt   = (const float*)d_in[1];
  float* out = (float*)d_out;

  uint4*        fmtb      = (uint4*)d_ws;                                  // 4 MB
  float*        blockSums = (float*)((char*)d_ws + (size_t)TOTAL_A * 32);  // +2 KB
  unsigned int* counter   = (unsigned int*)(blockSums + P1_BLOCKS);

  chamfer_fmt<<<TOTAL_A / BLK, BLK, 0, stream>>>(pred, gt, fmtb, counter);
  chamfer_mfma_pass1<<<P1_BLOCKS, BLK, 0, stream>>>(pred, gt, fmtb, blockSums,
                                                    counter, out);
}

// Round 6
// 102.129 us; speedup vs baseline: 16.0108x; 1.0192x over previous
//
#include <hip/hip_runtime.h>

// Chamfer loss, B=8, N=M=8192, D=3, fp32 I/O — MFMA R7 (resubmit; R5's
// bench was an infra failure — container acquire died, kernel never ran;
// audited: no spin-waits, all accesses in-bounds, 131KB/CU LDS fits).
//
// R6 post-mortem: spill gone (WRITE 29KB, VGPR 52) but 512 blocks =
// 2 waves/SIMD left the ds_read->mfma->fold chain latency exposed
// (MfmaUtil 24% == exactly our MFMA volume => 75% stall). R7 keeps the
// proven 2-chain inner loop BYTE-FOR-BYTE and only re-decomposes:
//   - NCH4=4: block = 256 a-pts x 2048 b-pts, 2048 blocks = 8 blocks/CU
//     = 8 waves/SIMD (LDS 2x8KB dbuf = 16.5KB/block, 8 fit).
//   - pass1 epilogue: xor32 + 2 partial writes (no reduction/atomic).
//   - pass2fin: float4 partial read -> d2 -> block sum -> atomic
//     last-block finish (R5/R6-proven). 3 dispatches.
//   - unchanged: pass0 fmt image, global_load_lds width-16 staging,
//     1 barrier/chunk, bijective XCD swizzle (2048 = 8*256).
//
//   v_mfma_f32_32x32x16_f16, K-slots (13/16), coords pre-scaled x16:
//     b (A-op): k0-7 = bh_x bh_y bh_z bl_x bl_y bl_z bh_x bh_y
//               k8-15 = bh_z ch cl 1 1 0 0 0          (c = -0.5|b|^2 split)
//     a (B-op): k0-7 = ah_x ah_y ah_z ah_x ah_y ah_z al_x al_y
//               k8-15 = al_z 1 1 dh dl 0 0 0          (d = -0.5|a|^2 split)
//   => v = -d2/2 (scaled 256); d2 = max_b(v) * (-1/128), clamp 0.

#define BATCH   8
#define NPTS    8192
#define BLK     256
#define TOTAL_A (2 * BATCH * NPTS)            // 131072
#define NCH4    4                             // b-quarters
#define BQUART  (NPTS / NCH4)                 // 2048
#define CHUNK   256                           // staged b-points per round
#define NCHUNK  (BQUART / CHUNK)              // 8
#define TPC     (CHUNK / 32)                  // 8 tiles per chunk
#define ABLKS   (NPTS / 256)                  // 32
#define P1_BLOCKS (2 * BATCH * ABLKS * NCH4)  // 2048
#define P2_BLOCKS (TOTAL_A / BLK)             // 512
#define SC      16.0f                         // exact pow2 coord scale

typedef _Float16 f16x8  __attribute__((ext_vector_type(8)));
typedef float    f32x16 __attribute__((ext_vector_type(16)));
typedef __attribute__((address_space(1))) const void gptr_t;
typedef __attribute__((address_space(3))) void lptr_t;

static __device__ __forceinline__ unsigned int pk2(float a, float b) {
  unsigned short ua = __builtin_bit_cast(unsigned short, (_Float16)a);
  unsigned short ub = __builtin_bit_cast(unsigned short, (_Float16)b);
  return (unsigned int)ua | ((unsigned int)ub << 16);
}

// 16 accumulator values + running max -> 8 v_max3_f32
static __device__ __forceinline__ float fold16(float mq, f32x16 d) {
  float t0 = fmaxf(fmaxf(d[0],  d[1]),  d[2]);
  float t1 = fmaxf(fmaxf(d[3],  d[4]),  d[5]);
  float t2 = fmaxf(fmaxf(d[6],  d[7]),  d[8]);
  float t3 = fmaxf(fmaxf(d[9],  d[10]), d[11]);
  float t4 = fmaxf(fmaxf(d[12], d[13]), d[14]);
  float t5 = fmaxf(fmaxf(t0, t1), t2);
  float t6 = fmaxf(fmaxf(t3, t4), d[15]);
  return fmaxf(fmaxf(mq, t5), t6);
}

// b-point -> A-operand fragment pair (byte-identical to R3/R5/R6)
static __device__ __forceinline__ void fmt_point(float X, float Y, float Z,
                                                 uint4* lo, uint4* hi) {
  float x = X * SC, y = Y * SC, z = Z * SC;
  float fx = (float)(_Float16)x, fy = (float)(_Float16)y, fz = (float)(_Float16)z;
  float lx = x - fx, ly = y - fy, lz = z - fz;
  float b2 = fmaf(x, x, fmaf(y, y, z * z));
  float c  = -0.5f * b2;
  float fc = (float)(_Float16)c;
  float lc = c - fc;
  *lo = make_uint4(pk2(x, y), pk2(z, lx), pk2(ly, lz), pk2(x, y));
  *hi = make_uint4(pk2(z, c), pk2(lc, 1.0f), 0x00003C00u, 0u);
}

// a-point -> B-operand fragment (col = lane&31, k-group = lane>>5)
static __device__ __forceinline__ f16x8 make_afrag(float X, float Y, float Z,
                                                   int hi) {
  float x = X * SC, y = Y * SC, z = Z * SC;
  float fx = (float)(_Float16)x, fy = (float)(_Float16)y, fz = (float)(_Float16)z;
  float lx = x - fx, ly = y - fy, lz = z - fz;
  float a2 = fmaf(x, x, fmaf(y, y, z * z));
  float dd = -0.5f * a2;
  float fd = (float)(_Float16)dd;
  float ld = dd - fd;
  uint4 u;
  if (!hi) {
    u = make_uint4(pk2(x, y), pk2(z, x), pk2(y, z), pk2(lx, ly));
  } else {
    u = make_uint4(pk2(lz, 1.0f), pk2(1.0f, dd), pk2(ld, 0.0f), 0u);
  }
  return __builtin_bit_cast(f16x8, u);
}

// pass0: format every point. Region = arr*8+batch (16384 uint4):
//   pt p: lo at region*16384 + (p>>5)*64 + (p&31), hi at +32.
__global__ __launch_bounds__(BLK) void chamfer_fmt(
    const float* __restrict__ pred, const float* __restrict__ gt,
    uint4* __restrict__ fmt, unsigned int* __restrict__ counter) {
  const int gid = blockIdx.x * BLK + threadIdx.x;   // [0, TOTAL_A)
  if (gid == 0) *counter = 0u;                      // reset for pass2fin
  const int arr = gid >> 16;                        // 0=pred, 1=gt
  const int idx = gid & 65535;
  const float* src = arr ? gt : pred;
  float X = src[(size_t)idx * 3 + 0];
  float Y = src[(size_t)idx * 3 + 1];
  float Z = src[(size_t)idx * 3 + 2];
  uint4 lo, hi;
  fmt_point(X, Y, Z, &lo, &hi);
  const int region = gid >> 13;
  const int p      = gid & 8191;
  size_t base = (size_t)region * 16384 + (size_t)(p >> 5) * 64 + (p & 31);
  fmt[base]      = lo;
  fmt[base + 32] = hi;
}

// stage one 8KB chunk (512 uint4) via global_load_lds; wave w owns
// uint4 [w*128, w*128+128): 2 calls x 64 lanes x 16B, linear order.
static __device__ __forceinline__ void stage_chunk(const uint4* src,
                                                   uint4* dst,
                                                   int wave, int lane) {
#pragma unroll
  for (int k = 0; k < 2; ++k) {
    const uint4* g = src + wave * 128 + k * 64 + lane;
    uint4*       l = dst + wave * 128 + k * 64;
    __builtin_amdgcn_global_load_lds((gptr_t*)g, (lptr_t*)l, 16, 0, 0);
  }
}

__global__ __launch_bounds__(BLK, 8) void chamfer_mfma_pass1(
    const float* __restrict__ pred, const float* __restrict__ gt,
    const uint4* __restrict__ fmt, float* __restrict__ partial) {
  __shared__ uint4 lds4[2 * 512];      // 2 x 8KB double buffer

  // bijective XCD swizzle (2048 = 8 * 256)
  const int swz   = ((blockIdx.x & 7) << 8) | (blockIdx.x >> 3);
  const int qc    = swz & 3;           // b-quarter
  const int r     = swz >> 2;
  const int ablk  = r & (ABLKS - 1);
  const int bd    = r >> 5;            // side*8 + batch
  const int batch = bd & 7;
  const int side  = bd >> 3;

  const float* A    = side ? gt : pred;
  const uint4* fmtB = fmt + (size_t)((1 - side) * 8 + batch) * 16384
                          + (size_t)qc * 4096;

  const int t    = threadIdx.x;
  const int lane = t & 63;
  const int wave = t >> 6;
  const int col  = lane & 31;
  const int hi   = lane >> 5;

  // R3/R6-proven shape: 2 named a-frags / 2 named accumulator chains
  const float* Ab = A + ((size_t)batch * NPTS + (size_t)ablk * 256 + (size_t)wave * 64) * 3;
  f16x8 af0 = make_afrag(Ab[col * 3 + 0], Ab[col * 3 + 1], Ab[col * 3 + 2], hi);
  f16x8 af1 = make_afrag(Ab[(32 + col) * 3 + 0], Ab[(32 + col) * 3 + 1],
                         Ab[(32 + col) * 3 + 2], hi);
  float mq0 = -3.0e38f, mq1 = -3.0e38f;
  const f32x16 zero = {};

  // prologue: stage chunk 0 into buffer 0
  stage_chunk(fmtB, lds4, wave, lane);
  __syncthreads();

  for (int c = 0; c < NCHUNK; ++c) {
    const uint4* rbuf = lds4 + (c & 1) * 512;
    // issue next chunk's DMA into the other buffer (prior barrier
    // guarantees everyone finished reading it)
    if (c + 1 < NCHUNK)
      stage_chunk(fmtB + (size_t)(c + 1) * 512, lds4 + ((c + 1) & 1) * 512,
                  wave, lane);

#pragma unroll
    for (int tt = 0; tt < TPC; ++tt) {
      f16x8 bf = *(const f16x8*)(rbuf + tt * 64 + lane);
      f32x16 d0 = __builtin_amdgcn_mfma_f32_32x32x16_f16(bf, af0, zero, 0, 0, 0);
      f32x16 d1 = __builtin_amdgcn_mfma_f32_32x32x16_f16(bf, af1, zero, 0, 0, 0);
      mq0 = fold16(mq0, d0);
      mq1 = fold16(mq1, d1);
    }
    __syncthreads();   // drains vmcnt -> next buffer ready for all waves
  }

  // lanes l, l+32: disjoint b-rows of the same a-col
  mq0 = fmaxf(mq0, __shfl_xor(mq0, 32));
  mq1 = fmaxf(mq1, __shfl_xor(mq1, 32));

  if (lane < 32) {
    size_t a0 = (size_t)bd * NPTS + (size_t)ablk * 256 + (size_t)wave * 64 + col;
    partial[a0 * NCH4 + qc]        = mq0;
    partial[(a0 + 32) * NCH4 + qc] = mq1;
  }
}

__global__ __launch_bounds__(BLK) void chamfer_pass2fin(
    const float4* __restrict__ partial, float* __restrict__ blockSums,
    unsigned int* __restrict__ counter, float* __restrict__ out) {
  __shared__ float wsum[BLK / 64];
  __shared__ int amLast;

  const int gid = blockIdx.x * BLK + threadIdx.x;   // [0, TOTAL_A)
  float4 p = partial[gid];
  float m  = fmaxf(fmaxf(p.x, p.y), fmaxf(p.z, p.w));
  // v = -d2_scaled/2, scale = 256  =>  d2 = m * (-1/128), clamp 0
  float d2 = fmaxf(m * (-1.0f / 128.0f), 0.0f);

  const int lane = threadIdx.x & 63, wave = threadIdx.x >> 6;
  float v = d2;
  for (int off = 32; off > 0; off >>= 1) v += __shfl_down(v, off);
  if (lane == 0) wsum[wave] = v;
  __syncthreads();
  if (threadIdx.x == 0) {
    float s = (wsum[0] + wsum[1]) + (wsum[2] + wsum[3]);
    blockSums[blockIdx.x] = s;
    __threadfence();
    unsigned int prev = atomicAdd(counter, 1u);
    amLast = (prev == P2_BLOCKS - 1);
  }
  __syncthreads();

  // deterministic final reduce by the last block
  if (amLast) {
    __threadfence();
    const volatile float* vbs = blockSums;
    float v2 = vbs[threadIdx.x] + vbs[threadIdx.x + 256];
    for (int off = 32; off > 0; off >>= 1) v2 += __shfl_down(v2, off);
    if (lane == 0) wsum[wave] = v2;
    __syncthreads();
    if (threadIdx.x == 0) {
      float s = ((wsum[0] + wsum[1]) + wsum[2]) + wsum[3];
      out[0] = s * (1.0f / (float)TOTAL_A);   // (sum1+sum2)/(2*65536)
    }
  }
}

extern "C" void kernel_launch(void* const* d_in, const int* in_sizes, int n_in,
                              void* d_out, int out_size, void* d_ws, size_t ws_size,
                              hipStream_t stream) {
  const float* pred = (const float*)d_in[0];
  const float* gt   = (const float*)d_in[1];
  float* out = (float*)d_out;

  uint4*        fmtb      = (uint4*)d_ws;                                  // 4 MB
  float*        partial   = (float*)((char*)d_ws + (size_t)TOTAL_A * 32);  // 2 MB
  float*        blockSums = partial + (size_t)TOTAL_A * NCH4;
  unsigned int* counter   = (unsigned int*)(blockSums + P2_BLOCKS);

  chamfer_fmt<<<TOTAL_A / BLK, BLK, 0, stream>>>(pred, gt, fmtb, counter);
  chamfer_mfma_pass1<<<P1_BLOCKS, BLK, 0, stream>>>(pred, gt, fmtb, partial);
  chamfer_pass2fin<<<P2_BLOCKS, BLK, 0, stream>>>((const float4*)partial,
                                                  blockSums, counter, out);
}